// Round 3
// baseline (1061.148 us; speedup 1.0000x reference)
//
#include <hip/hip_runtime.h>
#include <math.h>

// Problem constants
#define NB 32            // batch
#define CDIM 256         // channels / embedding dim
#define HW 1024          // H*W = 32*32
#define NROWS 32768      // NB*HW
#define KCODES 1024      // codebook size
#define ZELEMS 8388608   // NB*CDIM*HW

// Output layout (float32, concatenated in return order)
#define OUT_ZQ_OFF 0
#define OUT_IDX_OFF 8388608
#define OUT_LOSS_OFF 8421376
#define OUT_PERP_OFF 8421377

// Workspace layout (bytes)
#define WS_IDX_OFF 0            // int idx[32768]            (128 KB)
#define WS_CNT_OFF 131072       // uint counts[1024]         (4 KB)
#define WS_E2_OFF 135168        // double e2[1024]           (8 KB)
#define WS_LOSS_OFF 143360      // double loss_sum           (8 B)

// Argmin kernel tiling
#define BROWS 64   // rows per block
#define BCODES 64  // codes per chunk
#define BCDIM 32   // c-dims per staging chunk

__global__ __launch_bounds__(1024, 1) void zero_kernel(unsigned int* counts, double* loss_sum) {
    int t = threadIdx.x;
    if (t < KCODES) counts[t] = 0u;
    if (t == 0) loss_sum[0] = 0.0;
}

// e2[k] = sum_c embed[k][c]^2 in double. 1024 blocks x 64 threads.
__global__ __launch_bounds__(64) void e2_kernel(const float* __restrict__ embed,
                                                double* __restrict__ e2) {
    int k = blockIdx.x;
    int t = threadIdx.x;
    const float* row = embed + (size_t)k * CDIM;
    double s = 0.0;
    #pragma unroll
    for (int c = t; c < CDIM; c += 64) {
        double v = (double)row[c];
        s += v * v;
    }
    #pragma unroll
    for (int off = 32; off; off >>= 1) s += __shfl_down(s, off);
    if (t == 0) e2[k] = s;
}

// Fused distance + argmin kernel.
// Each block: 64 rows x all 1024 codes. X tile staged once in LDS (64KB).
// Double-precision accumulation -> true argmin (matches float64 np reference).
__global__ __launch_bounds__(256, 2) void argmin_kernel(
        const float* __restrict__ z_e, const float* __restrict__ embed,
        const double* __restrict__ e2, int* __restrict__ idx_out,
        float* __restrict__ idx_f_out, unsigned int* __restrict__ counts) {
    __shared__ float x_lds[CDIM][BROWS];        // [c][row] 64 KB
    __shared__ float b_lds[BCODES][BCDIM + 1];  // [k][c] padded: 8448 B
    __shared__ double e2c[BCODES];
    __shared__ double x2s[BROWS];
    __shared__ double bestd[BROWS];
    __shared__ int besti[BROWS];

    const int tid = threadIdx.x;
    const int tc = tid & 15;   // code group (16)
    const int tr = tid >> 4;   // row group (16)

    const int n0 = blockIdx.x * BROWS;
    const int b = n0 >> 10;        // / HW
    const int hw0 = n0 & (HW - 1);
    const float* xbase = z_e + (size_t)b * (CDIM * HW) + hw0;

    // Stage X tile: x_lds[c][r] = z_e[b][c][hw0+r] (coalesced 64-float rows)
    #pragma unroll
    for (int i = 0; i < (CDIM * BROWS) / 256; ++i) {
        int flat = i * 256 + tid;
        int c = flat >> 6;
        int r = flat & 63;
        x_lds[c][r] = xbase[(size_t)c * HW + r];
    }
    __syncthreads();

    // Per-row ||x||^2 in double
    if (tid < BROWS) {
        double s = 0.0;
        for (int c = 0; c < CDIM; ++c) {
            double v = (double)x_lds[c][tid];
            s += v * v;
        }
        x2s[tid] = s;
        bestd[tid] = 1e300;
        besti[tid] = 0;
    }

    for (int kc = 0; kc < KCODES; kc += BCODES) {
        __syncthreads();  // prev argmin-phase reads of e2c done; x2s/bestd init done
        if (tid < BCODES) e2c[tid] = e2[kc + tid];

        double acc[4][4];
        #pragma unroll
        for (int i = 0; i < 4; ++i)
            #pragma unroll
            for (int j = 0; j < 4; ++j) acc[i][j] = 0.0;

        for (int cc = 0; cc < CDIM; cc += BCDIM) {
            __syncthreads();  // prev compute reads of b_lds done (also covers e2c write)
            // Stage b_lds[k][c] = embed[kc+k][cc+c]; global reads coalesced (c fast)
            #pragma unroll
            for (int i = 0; i < (BCODES * BCDIM) / 256; ++i) {
                int flat = i * 256 + tid;
                int c = flat & (BCDIM - 1);
                int k = flat >> 5;
                b_lds[k][c] = embed[(size_t)(kc + k) * CDIM + cc + c];
            }
            __syncthreads();

            #pragma unroll
            for (int c = 0; c < BCDIM; ++c) {
                const float4 a4 = *reinterpret_cast<const float4*>(&x_lds[cc + c][tr * 4]);
                double ad0 = (double)a4.x, ad1 = (double)a4.y, ad2 = (double)a4.z, ad3 = (double)a4.w;
                double bd0 = (double)b_lds[tc * 4 + 0][c];
                double bd1 = (double)b_lds[tc * 4 + 1][c];
                double bd2 = (double)b_lds[tc * 4 + 2][c];
                double bd3 = (double)b_lds[tc * 4 + 3][c];
                acc[0][0] = fma(ad0, bd0, acc[0][0]);
                acc[0][1] = fma(ad0, bd1, acc[0][1]);
                acc[0][2] = fma(ad0, bd2, acc[0][2]);
                acc[0][3] = fma(ad0, bd3, acc[0][3]);
                acc[1][0] = fma(ad1, bd0, acc[1][0]);
                acc[1][1] = fma(ad1, bd1, acc[1][1]);
                acc[1][2] = fma(ad1, bd2, acc[1][2]);
                acc[1][3] = fma(ad1, bd3, acc[1][3]);
                acc[2][0] = fma(ad2, bd0, acc[2][0]);
                acc[2][1] = fma(ad2, bd1, acc[2][1]);
                acc[2][2] = fma(ad2, bd2, acc[2][2]);
                acc[2][3] = fma(ad2, bd3, acc[2][3]);
                acc[3][0] = fma(ad3, bd0, acc[3][0]);
                acc[3][1] = fma(ad3, bd1, acc[3][1]);
                acc[3][2] = fma(ad3, bd2, acc[3][2]);
                acc[3][3] = fma(ad3, bd3, acc[3][3]);
            }
        }

        // Per-thread 4x4 distances -> per-row best -> reduce across 16 code lanes
        #pragma unroll
        for (int i = 0; i < 4; ++i) {
            int row = tr * 4 + i;
            double x2 = x2s[row];
            double bd = 1e300;
            int bi = 0x7fffffff;
            #pragma unroll
            for (int j = 0; j < 4; ++j) {
                int k = kc + tc * 4 + j;
                double d = (x2 + e2c[tc * 4 + j]) - 2.0 * acc[i][j];
                if (d < bd || (d == bd && k < bi)) { bd = d; bi = k; }
            }
            #pragma unroll
            for (int off = 1; off < 16; off <<= 1) {
                double od = __shfl_xor(bd, off);
                int oi = __shfl_xor(bi, off);
                if (od < bd || (od == bd && oi < bi)) { bd = od; bi = oi; }
            }
            if (tc == 0) {
                // Only this lane ever touches this row's slot -> no race.
                if (bd < bestd[row]) { bestd[row] = bd; besti[row] = bi; }
            }
        }
    }

    __syncthreads();
    if (tid < BROWS) {
        int n = n0 + tid;
        int k = besti[tid];
        idx_out[n] = k;
        idx_f_out[n] = (float)k;
        atomicAdd(&counts[k], 1u);
    }
}

// Gather z_q, compute straight-through output exactly as reference
// (x + (q - x)), and accumulate sum((q-x)^2) in double.
__global__ __launch_bounds__(256) void gather_kernel(
        const float* __restrict__ z_e, const float* __restrict__ embed,
        const int* __restrict__ idx, float* __restrict__ out,
        double* __restrict__ loss_sum) {
    int o = blockIdx.x * 256 + threadIdx.x;  // < ZELEMS
    int hw = o & (HW - 1);
    int c = (o >> 10) & (CDIM - 1);
    int b = o >> 18;
    int n = (b << 10) | hw;
    int k = idx[n];
    float q = embed[(size_t)k * CDIM + c];
    float x = z_e[o];
    float r = q - x;          // z_q - z_e (fp32, mirrors reference rounding)
    out[o] = x + r;           // straight-through value
    double sq = (double)r * (double)r;

    // block reduce
    __shared__ double red[4];
    double s = sq;
    #pragma unroll
    for (int off = 32; off; off >>= 1) s += __shfl_down(s, off);
    if ((threadIdx.x & 63) == 0) red[threadIdx.x >> 6] = s;
    __syncthreads();
    if (threadIdx.x == 0) {
        double t = red[0] + red[1] + red[2] + red[3];
        atomicAdd(loss_sum, t);
    }
}

__global__ __launch_bounds__(256) void finalize_kernel(
        const unsigned int* __restrict__ counts, const double* __restrict__ loss_sum,
        float* __restrict__ out) {
    int tid = threadIdx.x;
    float H = 0.f;
    for (int k = tid; k < KCODES; k += 256) {
        float p = (float)counts[k] / 32768.0f;
        H += p * logf(p + 1e-10f);
    }
    __shared__ float hr[4];
    #pragma unroll
    for (int off = 32; off; off >>= 1) H += __shfl_down(H, off);
    if ((tid & 63) == 0) hr[tid >> 6] = H;
    __syncthreads();
    if (tid == 0) {
        float Hs = hr[0] + hr[1] + hr[2] + hr[3];
        out[OUT_LOSS_OFF] = (float)(0.25 * (loss_sum[0] / (double)ZELEMS));
        out[OUT_PERP_OFF] = expf(-Hs);
    }
}

extern "C" void kernel_launch(void* const* d_in, const int* in_sizes, int n_in,
                              void* d_out, int out_size, void* d_ws, size_t ws_size,
                              hipStream_t stream) {
    const float* z_e = (const float*)d_in[0];
    const float* embed = (const float*)d_in[1];
    float* out = (float*)d_out;

    char* ws = (char*)d_ws;
    int* ws_idx = (int*)(ws + WS_IDX_OFF);
    unsigned int* ws_cnt = (unsigned int*)(ws + WS_CNT_OFF);
    double* ws_e2 = (double*)(ws + WS_E2_OFF);
    double* ws_loss = (double*)(ws + WS_LOSS_OFF);

    zero_kernel<<<1, 1024, 0, stream>>>(ws_cnt, ws_loss);
    e2_kernel<<<KCODES, 64, 0, stream>>>(embed, ws_e2);
    argmin_kernel<<<NROWS / BROWS, 256, 0, stream>>>(z_e, embed, ws_e2, ws_idx,
                                                     out + OUT_IDX_OFF, ws_cnt);
    gather_kernel<<<ZELEMS / 256, 256, 0, stream>>>(z_e, embed, ws_idx, out + OUT_ZQ_OFF,
                                                    ws_loss);
    finalize_kernel<<<1, 256, 0, stream>>>(ws_cnt, ws_loss, out);
}

// Round 4
// 569.978 us; speedup vs baseline: 1.8617x; 1.8617x over previous
//
#include <hip/hip_runtime.h>
#include <math.h>

// Problem constants
#define NB 32            // batch
#define CDIM 256         // channels / embedding dim
#define HW 1024          // H*W = 32*32
#define NROWS 32768      // NB*HW
#define KCODES 1024      // codebook size
#define ZELEMS 8388608   // NB*CDIM*HW

// Output layout (float32, concatenated in return order)
#define OUT_ZQ_OFF 0
#define OUT_IDX_OFF 8388608
#define OUT_LOSS_OFF 8421376
#define OUT_PERP_OFF 8421377

// Workspace layout (bytes)
#define WS_IDX_OFF 0            // int idx[32768]            (128 KB)
#define WS_CNT_OFF 131072       // uint counts[1024]         (4 KB)
#define WS_E2D_OFF 135168       // double e2d[1024]          (8 KB)
#define WS_E2F_OFF 143360       // float e2f[1024]           (4 KB)
#define WS_LOSS_OFF 147456      // double loss_sum           (8 B)

// Argmin kernel tiling
#define BROWS 64   // rows per block
#define BCODES 64  // codes per chunk
#define BCDIM 32   // c-dims per staging chunk

// fp32 ambiguity margin: worst-case fp32 distance error ~1e-2; typical top-2
// gap ~15 -> expect ~0.5% of rows refined in fp64.
#define TAU 0.125f

__global__ __launch_bounds__(1024, 1) void zero_kernel(unsigned int* counts, double* loss_sum) {
    int t = threadIdx.x;
    if (t < KCODES) counts[t] = 0u;
    if (t == 0) loss_sum[0] = 0.0;
}

// e2[k] = sum_c embed[k][c]^2, written in double (refine path) and float (fast path).
__global__ __launch_bounds__(64) void e2_kernel(const float* __restrict__ embed,
                                                double* __restrict__ e2d,
                                                float* __restrict__ e2f) {
    int k = blockIdx.x;
    int t = threadIdx.x;
    const float* row = embed + (size_t)k * CDIM;
    double s = 0.0;
    #pragma unroll
    for (int c = t; c < CDIM; c += 64) {
        double v = (double)row[c];
        s += v * v;
    }
    #pragma unroll
    for (int off = 32; off; off >>= 1) s += __shfl_down(s, off);
    if (t == 0) { e2d[k] = s; e2f[k] = (float)s; }
}

// Fused distance + argmin kernel, fp32 fast path + fp64 refinement.
// Metric: d' = ||e||^2 - 2 x.e  (x^2 dropped: constant per row, argmin-invariant).
// Per block: 64 rows x all 1024 codes. X tile in LDS (64KB); B tile [c][k]
// transposed + XOR-swizzled so both operands load as ds_read_b128.
__global__ __launch_bounds__(256, 2) void argmin_kernel(
        const float* __restrict__ z_e, const float* __restrict__ embed,
        const float* __restrict__ e2f, const double* __restrict__ e2d,
        int* __restrict__ idx_out, float* __restrict__ idx_f_out,
        unsigned int* __restrict__ counts) {
    __shared__ float x_lds[CDIM][BROWS];    // [c][row] 64 KB
    __shared__ float b_lds[BCDIM][BCODES];  // [c][k], cols XOR-swizzled by (c&7) in 4-blocks: 8 KB
    __shared__ float e2c[BCODES];
    __shared__ int besti[BROWS];
    __shared__ float gaps[BROWS];
    __shared__ int amb_cnt;
    __shared__ int amb_rows[BROWS];
    __shared__ double red_d[4];
    __shared__ int red_i[4];

    const int tid = threadIdx.x;
    const int tc = tid & 15;   // code group (16) -> codes tc*4..tc*4+3 of chunk
    const int tr = tid >> 4;   // row group (16)  -> rows  tr*4..tr*4+3

    const int n0 = blockIdx.x * BROWS;
    const int b = n0 >> 10;
    const int hw0 = n0 & (HW - 1);
    const float* xbase = z_e + (size_t)b * (CDIM * HW) + hw0;

    // Stage X tile: x_lds[c][r] = z_e[b][c][hw0+r] (coalesced 64-float rows)
    #pragma unroll
    for (int i = 0; i < (CDIM * BROWS) / 256; ++i) {
        int flat = i * 256 + tid;
        int c = flat >> 6;
        int r = flat & 63;
        x_lds[c][r] = xbase[(size_t)c * HW + r];
    }
    if (tid == 0) amb_cnt = 0;

    // Preload B chunk 0 (chunk q: kc=(q>>3)*64 codes, cc=(q&7)*32 dims;
    // 2048 floats = 512 float4; thread loads float4 ids {tid, 256+tid}).
    float4 pre0, pre1;
    {
        int f0 = tid, f1 = 256 + tid;
        pre0 = *(const float4*)&embed[(size_t)(f0 >> 3) * CDIM + (f0 & 7) * 4];
        pre1 = *(const float4*)&embed[(size_t)(f1 >> 3) * CDIM + (f1 & 7) * 4];
    }

    float acc[4][4];
    float b1[4], b2[4];
    int i1[4];
    #pragma unroll
    for (int i = 0; i < 4; ++i) {
        b1[i] = 1e30f; b2[i] = 1e30f; i1[i] = 0x7fffffff;
        #pragma unroll
        for (int j = 0; j < 4; ++j) acc[i][j] = 0.f;
    }

    for (int q = 0; q < 128; ++q) {
        const int kcBase = (q >> 3) << 6;
        const int ccBase = (q & 7) << 5;

        __syncthreads();  // prev chunk's compute reads of b_lds done (also e2c reads)
        if ((q & 7) == 0 && tid < 64) e2c[tid] = e2f[kcBase + tid];

        // Store prefetched B chunk: element (lc, k) -> b_lds[lc][k ^ ((lc&7)<<2)]
        {
            int f0 = tid, f1 = 256 + tid;
            int k0 = f0 >> 3, lc0 = (f0 & 7) * 4;
            int k1 = f1 >> 3, lc1 = (f1 & 7) * 4;
            float v0[4] = {pre0.x, pre0.y, pre0.z, pre0.w};
            float v1[4] = {pre1.x, pre1.y, pre1.z, pre1.w};
            #pragma unroll
            for (int j = 0; j < 4; ++j) {
                int a0 = lc0 + j, a1 = lc1 + j;
                b_lds[a0][k0 ^ ((a0 & 7) << 2)] = v0[j];
                b_lds[a1][k1 ^ ((a1 & 7) << 2)] = v1[j];
            }
        }
        // Issue next chunk's global loads (completes under this chunk's compute)
        if (q < 127) {
            int qn = q + 1;
            int kcn = (qn >> 3) << 6, ccn = (qn & 7) << 5;
            int f0 = tid, f1 = 256 + tid;
            pre0 = *(const float4*)&embed[(size_t)(kcn + (f0 >> 3)) * CDIM + ccn + (f0 & 7) * 4];
            pre1 = *(const float4*)&embed[(size_t)(kcn + (f1 >> 3)) * CDIM + ccn + (f1 & 7) * 4];
        }
        __syncthreads();  // b_lds writes visible

        #pragma unroll
        for (int c = 0; c < BCDIM; ++c) {
            const float4 xv = *(const float4*)&x_lds[ccBase + c][tr * 4];
            const float4 bv = *(const float4*)&b_lds[c][(tc ^ (c & 7)) << 2];
            acc[0][0] = fmaf(xv.x, bv.x, acc[0][0]);
            acc[0][1] = fmaf(xv.x, bv.y, acc[0][1]);
            acc[0][2] = fmaf(xv.x, bv.z, acc[0][2]);
            acc[0][3] = fmaf(xv.x, bv.w, acc[0][3]);
            acc[1][0] = fmaf(xv.y, bv.x, acc[1][0]);
            acc[1][1] = fmaf(xv.y, bv.y, acc[1][1]);
            acc[1][2] = fmaf(xv.y, bv.z, acc[1][2]);
            acc[1][3] = fmaf(xv.y, bv.w, acc[1][3]);
            acc[2][0] = fmaf(xv.z, bv.x, acc[2][0]);
            acc[2][1] = fmaf(xv.z, bv.y, acc[2][1]);
            acc[2][2] = fmaf(xv.z, bv.z, acc[2][2]);
            acc[2][3] = fmaf(xv.z, bv.w, acc[2][3]);
            acc[3][0] = fmaf(xv.w, bv.x, acc[3][0]);
            acc[3][1] = fmaf(xv.w, bv.y, acc[3][1]);
            acc[3][2] = fmaf(xv.w, bv.z, acc[3][2]);
            acc[3][3] = fmaf(xv.w, bv.w, acc[3][3]);
        }

        if ((q & 7) == 7) {  // end of this kc's 256-dim accumulation: fold into top-2
            #pragma unroll
            for (int i = 0; i < 4; ++i) {
                #pragma unroll
                for (int j = 0; j < 4; ++j) {
                    int k = kcBase + tc * 4 + j;
                    float d = fmaf(-2.f, acc[i][j], e2c[tc * 4 + j]);
                    bool lt = (d < b1[i]) || (d == b1[i] && k < i1[i]);
                    b2[i] = lt ? b1[i] : fminf(b2[i], d);
                    if (lt) { b1[i] = d; i1[i] = k; }
                    acc[i][j] = 0.f;
                }
            }
        }
    }

    // Cross-lane merge of (b1,i1,b2) over the 16 code lanes (width 16)
    #pragma unroll
    for (int i = 0; i < 4; ++i) {
        #pragma unroll
        for (int off = 1; off < 16; off <<= 1) {
            float ob1 = __shfl_xor(b1[i], off, 16);
            int oi1 = __shfl_xor(i1[i], off, 16);
            float ob2 = __shfl_xor(b2[i], off, 16);
            bool take = (ob1 < b1[i]) || (ob1 == b1[i] && oi1 < i1[i]);
            float loser = take ? b1[i] : ob1;
            if (take) { b1[i] = ob1; i1[i] = oi1; }
            b2[i] = fminf(fminf(b2[i], ob2), loser);
        }
        if (tc == 0) {
            int row = tr * 4 + i;
            besti[row] = i1[i];
            gaps[row] = b2[i] - b1[i];
        }
    }
    __syncthreads();

    // Collect ambiguous rows (fp32 top-2 gap within TAU)
    if (tid < BROWS && gaps[tid] <= TAU) {
        int p = atomicAdd(&amb_cnt, 1);
        amb_rows[p] = tid;
    }
    __syncthreads();

    // fp64 exact refinement: whole block recomputes one row's 1024 distances
    for (int a = 0; a < amb_cnt; ++a) {
        int row = amb_rows[a];
        double bd = 1e300;
        int bi = 0x7fffffff;
        for (int jj = 0; jj < 4; ++jj) {
            int k = jj * 256 + tid;
            const float* er = embed + (size_t)k * CDIM;
            double dot = 0.0;
            for (int c = 0; c < CDIM; ++c)
                dot = fma((double)er[c], (double)x_lds[c][row], dot);
            double d = e2d[k] - 2.0 * dot;
            if (d < bd || (d == bd && k < bi)) { bd = d; bi = k; }
        }
        #pragma unroll
        for (int off = 1; off < 64; off <<= 1) {
            double od = __shfl_xor(bd, off);
            int oi = __shfl_xor(bi, off);
            if (od < bd || (od == bd && oi < bi)) { bd = od; bi = oi; }
        }
        if ((tid & 63) == 0) { red_d[tid >> 6] = bd; red_i[tid >> 6] = bi; }
        __syncthreads();
        if (tid == 0) {
            double fb = red_d[0]; int fi = red_i[0];
            #pragma unroll
            for (int w = 1; w < 4; ++w)
                if (red_d[w] < fb || (red_d[w] == fb && red_i[w] < fi)) { fb = red_d[w]; fi = red_i[w]; }
            besti[row] = fi;
        }
        __syncthreads();
    }

    if (tid < BROWS) {
        int n = n0 + tid;
        int k = besti[tid];
        idx_out[n] = k;
        idx_f_out[n] = (float)k;
        atomicAdd(&counts[k], 1u);
    }
}

// Gather z_q, straight-through output (x + (q - x), fp32 like reference),
// and sum((q-x)^2) in double. float4/int4 loads; ONE fp64 atomic per block.
#define GBLOCKS 1024
#define GITERS 8  // 1024 blocks * 256 thr * 8 * 4 elems = 8388608
__global__ __launch_bounds__(256) void gather_kernel(
        const float* __restrict__ z_e, const float* __restrict__ embed,
        const int* __restrict__ idx, float* __restrict__ out,
        double* __restrict__ loss_sum) {
    double sacc = 0.0;
    #pragma unroll
    for (int it = 0; it < GITERS; ++it) {
        int f = (blockIdx.x * GITERS + it) * 256 + threadIdx.x;  // float4 id
        int o = f << 2;
        int hw = o & (HW - 1);
        int c = (o >> 10) & (CDIM - 1);
        int b = o >> 18;
        int n0 = (b << 10) | hw;
        int4 k4 = *(const int4*)&idx[n0];
        float4 x4 = *(const float4*)&z_e[o];
        float q0 = embed[(size_t)k4.x * CDIM + c];
        float q1 = embed[(size_t)k4.y * CDIM + c];
        float q2 = embed[(size_t)k4.z * CDIM + c];
        float q3 = embed[(size_t)k4.w * CDIM + c];
        float r0 = q0 - x4.x, r1 = q1 - x4.y, r2 = q2 - x4.z, r3 = q3 - x4.w;
        float4 o4 = make_float4(x4.x + r0, x4.y + r1, x4.z + r2, x4.w + r3);
        *(float4*)&out[o] = o4;
        sacc += (double)r0 * r0 + (double)r1 * r1 + (double)r2 * r2 + (double)r3 * r3;
    }
    __shared__ double red[4];
    #pragma unroll
    for (int off = 32; off; off >>= 1) sacc += __shfl_down(sacc, off);
    if ((threadIdx.x & 63) == 0) red[threadIdx.x >> 6] = sacc;
    __syncthreads();
    if (threadIdx.x == 0)
        atomicAdd(loss_sum, red[0] + red[1] + red[2] + red[3]);
}

__global__ __launch_bounds__(256) void finalize_kernel(
        const unsigned int* __restrict__ counts, const double* __restrict__ loss_sum,
        float* __restrict__ out) {
    int tid = threadIdx.x;
    float H = 0.f;
    for (int k = tid; k < KCODES; k += 256) {
        float p = (float)counts[k] / 32768.0f;
        H += p * logf(p + 1e-10f);
    }
    __shared__ float hr[4];
    #pragma unroll
    for (int off = 32; off; off >>= 1) H += __shfl_down(H, off);
    if ((tid & 63) == 0) hr[tid >> 6] = H;
    __syncthreads();
    if (tid == 0) {
        float Hs = hr[0] + hr[1] + hr[2] + hr[3];
        out[OUT_LOSS_OFF] = (float)(0.25 * (loss_sum[0] / (double)ZELEMS));
        out[OUT_PERP_OFF] = expf(-Hs);
    }
}

extern "C" void kernel_launch(void* const* d_in, const int* in_sizes, int n_in,
                              void* d_out, int out_size, void* d_ws, size_t ws_size,
                              hipStream_t stream) {
    const float* z_e = (const float*)d_in[0];
    const float* embed = (const float*)d_in[1];
    float* out = (float*)d_out;

    char* ws = (char*)d_ws;
    int* ws_idx = (int*)(ws + WS_IDX_OFF);
    unsigned int* ws_cnt = (unsigned int*)(ws + WS_CNT_OFF);
    double* ws_e2d = (double*)(ws + WS_E2D_OFF);
    float* ws_e2f = (float*)(ws + WS_E2F_OFF);
    double* ws_loss = (double*)(ws + WS_LOSS_OFF);

    zero_kernel<<<1, 1024, 0, stream>>>(ws_cnt, ws_loss);
    e2_kernel<<<KCODES, 64, 0, stream>>>(embed, ws_e2d, ws_e2f);
    argmin_kernel<<<NROWS / BROWS, 256, 0, stream>>>(z_e, embed, ws_e2f, ws_e2d, ws_idx,
                                                     out + OUT_IDX_OFF, ws_cnt);
    gather_kernel<<<GBLOCKS, 256, 0, stream>>>(z_e, embed, ws_idx, out + OUT_ZQ_OFF,
                                               ws_loss);
    finalize_kernel<<<1, 256, 0, stream>>>(ws_cnt, ws_loss, out);
}

// Round 5
// 507.454 us; speedup vs baseline: 2.0911x; 1.1232x over previous
//
#include <hip/hip_runtime.h>
#include <math.h>

// Problem constants
#define NB 32            // batch
#define CDIM 256         // channels / embedding dim
#define HW 1024          // H*W = 32*32
#define NROWS 32768      // NB*HW
#define KCODES 1024      // codebook size
#define ZELEMS 8388608   // NB*CDIM*HW

// Output layout (float32, concatenated in return order)
#define OUT_ZQ_OFF 0
#define OUT_IDX_OFF 8388608
#define OUT_LOSS_OFF 8421376
#define OUT_PERP_OFF 8421377

// Workspace layout (bytes)
#define WS_IDX_OFF 0            // int idx[32768]            (128 KB)
#define WS_CNT_OFF 131072       // uint counts[1024]         (4 KB)
#define WS_E2D_OFF 135168       // double e2d[1024]          (8 KB)
#define WS_E2F_OFF 143360       // float e2f[1024]           (4 KB)
#define WS_LOSS_OFF 147456      // double loss_sum           (8 B)

// Argmin kernel tiling: 64 rows x 1024 codes per block; 8x8 register tile.
#define BROWS 64
#define BCODES 256  // codes per kc chunk (4 chunks)
#define BCDIM 8     // c-dims per stage (32 stages per chunk; 128 total)

// fp32 ambiguity margin: fp32 dot error <= ~3e-3; typical top-2 gap ~14.
#define TAU 0.125f

__global__ __launch_bounds__(1024, 1) void zero_kernel(unsigned int* counts, double* loss_sum) {
    int t = threadIdx.x;
    if (t < KCODES) counts[t] = 0u;
    if (t == 0) loss_sum[0] = 0.0;
}

// e2[k] = sum_c embed[k][c]^2, double (refine path) + float (fast path).
__global__ __launch_bounds__(64) void e2_kernel(const float* __restrict__ embed,
                                                double* __restrict__ e2d,
                                                float* __restrict__ e2f) {
    int k = blockIdx.x;
    int t = threadIdx.x;
    const float* row = embed + (size_t)k * CDIM;
    double s = 0.0;
    #pragma unroll
    for (int c = t; c < CDIM; c += 64) {
        double v = (double)row[c];
        s += v * v;
    }
    #pragma unroll
    for (int off = 32; off; off >>= 1) s += __shfl_down(s, off);
    if (t == 0) { e2d[k] = s; e2f[k] = (float)s; }
}

// Fused distance + argmin. Metric d' = ||e||^2 - 2 x.e (x^2 argmin-invariant).
// 8 rows x 8 codes per thread: per c, 64B LDS read per 64 FMA (1 B/FMA).
// Lane tc owns code quads {4tc, 128+4tc} -> B reads are 2-way bank (free),
// x reads broadcast within 32-lane groups (free). Plain [c][k] B layout.
__global__ __launch_bounds__(256, 2) void argmin_kernel(
        const float* __restrict__ z_e, const float* __restrict__ embed,
        const float* __restrict__ e2f, const double* __restrict__ e2d,
        int* __restrict__ idx_out, float* __restrict__ idx_f_out,
        unsigned int* __restrict__ counts) {
    __shared__ float x_lds[CDIM][BROWS];    // [c][row] 64 KB
    __shared__ float b_lds[BCDIM][BCODES];  // [c][k] 8 KB
    __shared__ float e2c[BCODES];           // 1 KB
    __shared__ int besti[BROWS];
    __shared__ float gaps[BROWS];
    __shared__ int amb_cnt;
    __shared__ int amb_rows[BROWS];
    __shared__ double red_d[4];
    __shared__ int red_i[4];

    const int tid = threadIdx.x;
    const int tc = tid & 31;   // code group: quads {4tc, 128+4tc} of chunk
    const int tr = tid >> 5;   // row group: rows tr*8 .. tr*8+7

    const int n0 = blockIdx.x * BROWS;
    const int b = n0 >> 10;
    const int hw0 = n0 & (HW - 1);
    const float* xbase = z_e + (size_t)b * (CDIM * HW) + hw0;

    // Stage X tile: x_lds[c][r] = z_e[b][c][hw0+r] (coalesced, conflict-free)
    #pragma unroll
    for (int i = 0; i < (CDIM * BROWS) / 256; ++i) {
        int flat = i * 256 + tid;
        int c = flat >> 6;
        int r = flat & 63;
        x_lds[c][r] = xbase[(size_t)c * HW + r];
    }
    if (tid == 0) amb_cnt = 0;

    // Stage q (0..127): chunk = q>>5 (kcBase = chunk*256), ccBase = (q&31)*8.
    // Stage = 2048 floats = 512 float4; thread loads float4 ids {tid, 256+tid}:
    // f -> (k = f>>1, chalf = (f&1)*4): embed[kcBase+k][ccBase+chalf .. +3].
    float4 pre0, pre1;
    {
        int f0 = tid, f1 = 256 + tid;
        pre0 = *(const float4*)&embed[(size_t)(f0 >> 1) * CDIM + (f0 & 1) * 4];
        pre1 = *(const float4*)&embed[(size_t)(f1 >> 1) * CDIM + (f1 & 1) * 4];
    }

    float acc[8][8];
    float b1[8], b2[8];
    int i1[8];
    #pragma unroll
    for (int i = 0; i < 8; ++i) {
        b1[i] = 1e30f; b2[i] = 1e30f; i1[i] = 0x7fffffff;
        #pragma unroll
        for (int j = 0; j < 8; ++j) acc[i][j] = 0.f;
    }

    for (int q = 0; q < 128; ++q) {
        const int kcBase = (q >> 5) << 8;
        const int ccBase = (q & 31) << 3;

        __syncthreads();  // prev stage's b_lds/e2c reads done
        if ((q & 31) == 0) e2c[tid] = e2f[kcBase + tid];

        // Store prefetched B stage: float4 f covers c=chalf..chalf+3 of row k
        {
            int k0 = tid >> 1, ch0 = (tid & 1) * 4;
            int k1 = (256 + tid) >> 1, ch1 = ((256 + tid) & 1) * 4;
            float v0[4] = {pre0.x, pre0.y, pre0.z, pre0.w};
            float v1[4] = {pre1.x, pre1.y, pre1.z, pre1.w};
            #pragma unroll
            for (int j = 0; j < 4; ++j) {
                b_lds[ch0 + j][k0] = v0[j];
                b_lds[ch1 + j][k1] = v1[j];
            }
        }
        // Issue next stage's global loads (complete under this stage's compute)
        if (q < 127) {
            int qn = q + 1;
            int kcn = (qn >> 5) << 8, ccn = (qn & 31) << 3;
            int f0 = tid, f1 = 256 + tid;
            pre0 = *(const float4*)&embed[(size_t)(kcn + (f0 >> 1)) * CDIM + ccn + (f0 & 1) * 4];
            pre1 = *(const float4*)&embed[(size_t)(kcn + (f1 >> 1)) * CDIM + ccn + (f1 & 1) * 4];
        }
        __syncthreads();  // b_lds writes visible

        #pragma unroll
        for (int cL = 0; cL < BCDIM; ++cL) {
            const int cG = ccBase + cL;
            const float4 xv0 = *(const float4*)&x_lds[cG][tr * 8];
            const float4 xv1 = *(const float4*)&x_lds[cG][tr * 8 + 4];
            const float4 bv0 = *(const float4*)&b_lds[cL][tc * 4];
            const float4 bv1 = *(const float4*)&b_lds[cL][128 + tc * 4];
            const float xs[8] = {xv0.x, xv0.y, xv0.z, xv0.w, xv1.x, xv1.y, xv1.z, xv1.w};
            const float bs[8] = {bv0.x, bv0.y, bv0.z, bv0.w, bv1.x, bv1.y, bv1.z, bv1.w};
            #pragma unroll
            for (int i = 0; i < 8; ++i)
                #pragma unroll
                for (int j = 0; j < 8; ++j)
                    acc[i][j] = fmaf(xs[i], bs[j], acc[i][j]);
        }

        if ((q & 31) == 31) {  // end of chunk: fold 8 codes into per-row top-2
            #pragma unroll
            for (int i = 0; i < 8; ++i) {
                #pragma unroll
                for (int j = 0; j < 8; ++j) {
                    int kl = (j < 4) ? (tc * 4 + j) : (128 + tc * 4 + (j - 4));
                    int k = kcBase + kl;
                    float d = fmaf(-2.f, acc[i][j], e2c[kl]);
                    bool lt = (d < b1[i]) || (d == b1[i] && k < i1[i]);
                    b2[i] = lt ? b1[i] : fminf(b2[i], d);
                    if (lt) { b1[i] = d; i1[i] = k; }
                    acc[i][j] = 0.f;
                }
            }
        }
    }

    // Merge (b1,i1,b2) across the 32 code lanes of each row group
    #pragma unroll
    for (int i = 0; i < 8; ++i) {
        #pragma unroll
        for (int off = 1; off < 32; off <<= 1) {
            float ob1 = __shfl_xor(b1[i], off, 32);
            int oi1 = __shfl_xor(i1[i], off, 32);
            float ob2 = __shfl_xor(b2[i], off, 32);
            bool take = (ob1 < b1[i]) || (ob1 == b1[i] && oi1 < i1[i]);
            float loser = take ? b1[i] : ob1;
            if (take) { b1[i] = ob1; i1[i] = oi1; }
            b2[i] = fminf(fminf(b2[i], ob2), loser);
        }
        if (tc == 0) {
            int row = tr * 8 + i;
            besti[row] = i1[i];
            gaps[row] = b2[i] - b1[i];
        }
    }
    __syncthreads();

    // Collect ambiguous rows (fp32 top-2 gap within TAU)
    if (tid < BROWS && gaps[tid] <= TAU) {
        int p = atomicAdd(&amb_cnt, 1);
        amb_rows[p] = tid;
    }
    __syncthreads();

    // fp64 exact refinement: block recomputes one row's 1024 distances
    for (int a = 0; a < amb_cnt; ++a) {
        int row = amb_rows[a];
        double bd = 1e300;
        int bi = 0x7fffffff;
        for (int jj = 0; jj < 4; ++jj) {
            int k = jj * 256 + tid;
            const float* er = embed + (size_t)k * CDIM;
            double dot = 0.0;
            for (int c = 0; c < CDIM; ++c)
                dot = fma((double)er[c], (double)x_lds[c][row], dot);
            double d = e2d[k] - 2.0 * dot;
            if (d < bd || (d == bd && k < bi)) { bd = d; bi = k; }
        }
        #pragma unroll
        for (int off = 1; off < 64; off <<= 1) {
            double od = __shfl_xor(bd, off);
            int oi = __shfl_xor(bi, off);
            if (od < bd || (od == bd && oi < bi)) { bd = od; bi = oi; }
        }
        if ((tid & 63) == 0) { red_d[tid >> 6] = bd; red_i[tid >> 6] = bi; }
        __syncthreads();
        if (tid == 0) {
            double fb = red_d[0]; int fi = red_i[0];
            #pragma unroll
            for (int w = 1; w < 4; ++w)
                if (red_d[w] < fb || (red_d[w] == fb && red_i[w] < fi)) { fb = red_d[w]; fi = red_i[w]; }
            besti[row] = fi;
        }
        __syncthreads();
    }

    if (tid < BROWS) {
        int n = n0 + tid;
        int k = besti[tid];
        idx_out[n] = k;
        idx_f_out[n] = (float)k;
        atomicAdd(&counts[k], 1u);
    }
}

// Gather z_q, straight-through output (x + (q - x), fp32 like reference),
// and sum((q-x)^2) in double. float4/int4 loads; ONE fp64 atomic per block.
#define GBLOCKS 1024
#define GITERS 8  // 1024 blocks * 256 thr * 8 * 4 elems = 8388608
__global__ __launch_bounds__(256) void gather_kernel(
        const float* __restrict__ z_e, const float* __restrict__ embed,
        const int* __restrict__ idx, float* __restrict__ out,
        double* __restrict__ loss_sum) {
    double sacc = 0.0;
    #pragma unroll
    for (int it = 0; it < GITERS; ++it) {
        int f = (blockIdx.x * GITERS + it) * 256 + threadIdx.x;  // float4 id
        int o = f << 2;
        int hw = o & (HW - 1);
        int c = (o >> 10) & (CDIM - 1);
        int b = o >> 18;
        int n0 = (b << 10) | hw;
        int4 k4 = *(const int4*)&idx[n0];
        float4 x4 = *(const float4*)&z_e[o];
        float q0 = embed[(size_t)k4.x * CDIM + c];
        float q1 = embed[(size_t)k4.y * CDIM + c];
        float q2 = embed[(size_t)k4.z * CDIM + c];
        float q3 = embed[(size_t)k4.w * CDIM + c];
        float r0 = q0 - x4.x, r1 = q1 - x4.y, r2 = q2 - x4.z, r3 = q3 - x4.w;
        float4 o4 = make_float4(x4.x + r0, x4.y + r1, x4.z + r2, x4.w + r3);
        *(float4*)&out[o] = o4;
        sacc += (double)r0 * r0 + (double)r1 * r1 + (double)r2 * r2 + (double)r3 * r3;
    }
    __shared__ double red[4];
    #pragma unroll
    for (int off = 32; off; off >>= 1) sacc += __shfl_down(sacc, off);
    if ((threadIdx.x & 63) == 0) red[threadIdx.x >> 6] = sacc;
    __syncthreads();
    if (threadIdx.x == 0)
        atomicAdd(loss_sum, red[0] + red[1] + red[2] + red[3]);
}

__global__ __launch_bounds__(256) void finalize_kernel(
        const unsigned int* __restrict__ counts, const double* __restrict__ loss_sum,
        float* __restrict__ out) {
    int tid = threadIdx.x;
    float H = 0.f;
    for (int k = tid; k < KCODES; k += 256) {
        float p = (float)counts[k] / 32768.0f;
        H += p * logf(p + 1e-10f);
    }
    __shared__ float hr[4];
    #pragma unroll
    for (int off = 32; off; off >>= 1) H += __shfl_down(H, off);
    if ((tid & 63) == 0) hr[tid >> 6] = H;
    __syncthreads();
    if (tid == 0) {
        float Hs = hr[0] + hr[1] + hr[2] + hr[3];
        out[OUT_LOSS_OFF] = (float)(0.25 * (loss_sum[0] / (double)ZELEMS));
        out[OUT_PERP_OFF] = expf(-Hs);
    }
}

extern "C" void kernel_launch(void* const* d_in, const int* in_sizes, int n_in,
                              void* d_out, int out_size, void* d_ws, size_t ws_size,
                              hipStream_t stream) {
    const float* z_e = (const float*)d_in[0];
    const float* embed = (const float*)d_in[1];
    float* out = (float*)d_out;

    char* ws = (char*)d_ws;
    int* ws_idx = (int*)(ws + WS_IDX_OFF);
    unsigned int* ws_cnt = (unsigned int*)(ws + WS_CNT_OFF);
    double* ws_e2d = (double*)(ws + WS_E2D_OFF);
    float* ws_e2f = (float*)(ws + WS_E2F_OFF);
    double* ws_loss = (double*)(ws + WS_LOSS_OFF);

    zero_kernel<<<1, 1024, 0, stream>>>(ws_cnt, ws_loss);
    e2_kernel<<<KCODES, 64, 0, stream>>>(embed, ws_e2d, ws_e2f);
    argmin_kernel<<<NROWS / BROWS, 256, 0, stream>>>(z_e, embed, ws_e2f, ws_e2d, ws_idx,
                                                     out + OUT_IDX_OFF, ws_cnt);
    gather_kernel<<<GBLOCKS, 256, 0, stream>>>(z_e, embed, ws_idx, out + OUT_ZQ_OFF,
                                               ws_loss);
    finalize_kernel<<<1, 256, 0, stream>>>(ws_cnt, ws_loss, out);
}

// Round 6
// 489.830 us; speedup vs baseline: 2.1664x; 1.0360x over previous
//
#include <hip/hip_runtime.h>
#include <math.h>

typedef __attribute__((ext_vector_type(8))) short short8;  // 8 bf16 (4 VGPR)
typedef __attribute__((ext_vector_type(4))) float f32x4;   // MFMA C/D

// Problem constants
#define NB 32
#define CDIM 256
#define HW 1024
#define NROWS 32768
#define KCODES 1024
#define ZELEMS 8388608

// Output layout (float32, concatenated)
#define OUT_ZQ_OFF 0
#define OUT_IDX_OFF 8388608
#define OUT_LOSS_OFF 8421376
#define OUT_PERP_OFF 8421377

// Workspace layout (bytes)
#define WS_IDX_OFF 0            // int idx[32768]
#define WS_CNT_OFF 131072       // uint counts[1024]
#define WS_E2D_OFF 135168       // double e2d[1024]
#define WS_E2F_OFF 143360       // float e2f[1024]
#define WS_LOSS_OFF 147456      // double loss_sum
#define WS_EHI_OFF 262144       // bf16 e_hi[1024][256] (512 KB)
#define WS_ELO_OFF 786432       // bf16 e_lo[1024][256] (512 KB)
// total ~1.25 MB

// fp32-accum MFMA distance error (4-product hi/lo split): worst ~1e-2.
#define TAU 0.25f

__device__ inline ushort f2bf(float f) {  // fp32 -> bf16 bits, RNE
    unsigned u = __float_as_uint(f);
    unsigned r = (u + 0x7FFFu + ((u >> 16) & 1u)) >> 16;
    return (ushort)r;
}

__global__ __launch_bounds__(1024, 1) void zero_kernel(unsigned* counts, double* loss_sum) {
    int t = threadIdx.x;
    if (t < KCODES) counts[t] = 0u;
    if (t == 0) loss_sum[0] = 0.0;
}

// Per code k: e2 (double+float) and bf16 hi/lo split of embed row.
__global__ __launch_bounds__(64) void e2split_kernel(const float* __restrict__ embed,
                                                     double* __restrict__ e2d,
                                                     float* __restrict__ e2f,
                                                     ushort* __restrict__ ehi,
                                                     ushort* __restrict__ elo) {
    int k = blockIdx.x, t = threadIdx.x;
    float4 v = *(const float4*)&embed[(size_t)k * CDIM + 4 * t];
    double s = (double)v.x * v.x + (double)v.y * v.y + (double)v.z * v.z + (double)v.w * v.w;
    #pragma unroll
    for (int off = 32; off; off >>= 1) s += __shfl_down(s, off);
    if (t == 0) { e2d[k] = s; e2f[k] = (float)s; }
    float xs[4] = {v.x, v.y, v.z, v.w};
    ushort h[4], lo[4];
    #pragma unroll
    for (int j = 0; j < 4; ++j) {
        h[j] = f2bf(xs[j]);
        float hf = __uint_as_float(((unsigned)h[j]) << 16);
        lo[j] = f2bf(xs[j] - hf);
    }
    uint2 hh, ll;
    hh.x = (unsigned)h[0] | ((unsigned)h[1] << 16);
    hh.y = (unsigned)h[2] | ((unsigned)h[3] << 16);
    ll.x = (unsigned)lo[0] | ((unsigned)lo[1] << 16);
    ll.y = (unsigned)lo[2] | ((unsigned)lo[3] << 16);
    *(uint2*)&ehi[(size_t)k * CDIM + 4 * t] = hh;
    *(uint2*)&elo[(size_t)k * CDIM + 4 * t] = ll;
}

// MFMA distance + argmin. 512 thr (8 waves), 64 rows x 1024 codes per block.
// d' = e2 - 2 x.e via 4x bf16 MFMA (hi/lo split), fp64 refine of near-ties.
__global__ __launch_bounds__(512, 2) void argmin_kernel(
        const float* __restrict__ z_e, const float* __restrict__ embed,
        const ushort* __restrict__ ehi, const ushort* __restrict__ elo,
        const float* __restrict__ e2f, const double* __restrict__ e2d,
        int* __restrict__ idx_out, float* __restrict__ idx_f_out,
        unsigned* __restrict__ counts) {
    __shared__ __align__(16) float x_lds[64 * 256];  // [row][c ^ ((row&7)<<2)] 64 KB
    __shared__ float mb1[8][64], mb2[8][64];
    __shared__ int mi1[8][64];
    __shared__ int besti[64];
    __shared__ float gaps[64];
    __shared__ int amb_cnt;
    __shared__ int amb_rows[64];
    __shared__ double red_d[8];
    __shared__ int red_i[8];

    const int tid = threadIdx.x;
    const int w = tid >> 6;       // wave 0..7 -> codes w*128..w*128+127
    const int l = tid & 63;
    const int l15 = l & 15, l4 = l >> 4;

    const int n0 = blockIdx.x * 64;
    const float* xbase = z_e + (size_t)(n0 >> 10) * (CDIM * HW) + (n0 & (HW - 1));

    // Stage x tile fp32, swizzled [row][c]: coalesced global float4 over hw.
    #pragma unroll
    for (int i = 0; i < 8; ++i) {
        int f4 = i * 512 + tid;
        int c = f4 >> 4;
        int r4 = (f4 & 15) << 2;
        float4 v = *(const float4*)&xbase[(size_t)c * HW + r4];
        x_lds[(r4 + 0) * 256 + (c ^ (((r4 + 0) & 7) << 2))] = v.x;
        x_lds[(r4 + 1) * 256 + (c ^ (((r4 + 1) & 7) << 2))] = v.y;
        x_lds[(r4 + 2) * 256 + (c ^ (((r4 + 2) & 7) << 2))] = v.z;
        x_lds[(r4 + 3) * 256 + (c ^ (((r4 + 3) & 7) << 2))] = v.w;
    }
    if (tid == 0) amb_cnt = 0;
    __syncthreads();

    f32x4 acc[4][8];
    #pragma unroll
    for (int rt = 0; rt < 4; ++rt)
        #pragma unroll
        for (int ctl = 0; ctl < 8; ++ctl)
            acc[rt][ctl] = (f32x4){0.f, 0.f, 0.f, 0.f};

    const short8* eh8 = (const short8*)ehi;
    const short8* el8 = (const short8*)elo;
    const int lb = l15 * 32 + l4;  // lane part of B offset (short8 units)

    for (int ks = 0; ks < 8; ++ks) {
        // Build A-frags (hi/lo) for 4 row-tiles from LDS (2x ds_read_b128 each)
        short8 ah[4], al[4];
        #pragma unroll
        for (int rt = 0; rt < 4; ++rt) {
            int arow = rt * 16 + l15;
            int sw = (arow & 7) << 2;
            int base = arow * 256;
            int c0 = ks * 32 + l4 * 8;
            float4 xa = *(const float4*)&x_lds[base + ((c0) ^ sw)];
            float4 xb = *(const float4*)&x_lds[base + ((c0 + 4) ^ sw)];
            float xs[8] = {xa.x, xa.y, xa.z, xa.w, xb.x, xb.y, xb.z, xb.w};
            #pragma unroll
            for (int e = 0; e < 8; ++e) {
                ushort h = f2bf(xs[e]);
                float hf = __uint_as_float(((unsigned)h) << 16);
                ushort lo = f2bf(xs[e] - hf);
                ah[rt][e] = (short)h;
                al[rt][e] = (short)lo;
            }
        }
        #pragma unroll
        for (int ctl = 0; ctl < 8; ++ctl) {
            int off = (w * 8 + ctl) * 512 + ks * 4 + lb;  // = (ct*16+l15)*32 + ks*4 + l4
            short8 bh = eh8[off];
            short8 bl = el8[off];
            #pragma unroll
            for (int rt = 0; rt < 4; ++rt) {
                acc[rt][ctl] = __builtin_amdgcn_mfma_f32_16x16x32_bf16(ah[rt], bh, acc[rt][ctl], 0, 0, 0);
                acc[rt][ctl] = __builtin_amdgcn_mfma_f32_16x16x32_bf16(ah[rt], bl, acc[rt][ctl], 0, 0, 0);
                acc[rt][ctl] = __builtin_amdgcn_mfma_f32_16x16x32_bf16(al[rt], bh, acc[rt][ctl], 0, 0, 0);
                acc[rt][ctl] = __builtin_amdgcn_mfma_f32_16x16x32_bf16(al[rt], bl, acc[rt][ctl], 0, 0, 0);
            }
        }
    }

    // Fold: lane holds (row = rt*16 + l4*4 + r, code = w*128 + ctl*16 + l15).
    float tb1[16], tb2[16];
    int ti1[16];
    #pragma unroll
    for (int s = 0; s < 16; ++s) { tb1[s] = 1e30f; tb2[s] = 1e30f; ti1[s] = 0x7fffffff; }
    #pragma unroll
    for (int ctl = 0; ctl < 8; ++ctl) {
        int k = w * 128 + ctl * 16 + l15;
        float e2v = e2f[k];
        #pragma unroll
        for (int rt = 0; rt < 4; ++rt) {
            #pragma unroll
            for (int r = 0; r < 4; ++r) {
                float d = fmaf(-2.f, acc[rt][ctl][r], e2v);
                int s = rt * 4 + r;
                bool lt = (d < tb1[s]);  // k ascending in ctl -> strict < keeps smallest k on ties
                tb2[s] = lt ? tb1[s] : fminf(tb2[s], d);
                if (lt) { tb1[s] = d; ti1[s] = k; }
            }
        }
    }
    // Reduce across 16 lanes sharing the same rows (different codes)
    #pragma unroll
    for (int s = 0; s < 16; ++s) {
        #pragma unroll
        for (int off = 1; off < 16; off <<= 1) {
            float ob1 = __shfl_xor(tb1[s], off, 16);
            int oi1 = __shfl_xor(ti1[s], off, 16);
            float ob2 = __shfl_xor(tb2[s], off, 16);
            bool take = (ob1 < tb1[s]) || (ob1 == tb1[s] && oi1 < ti1[s]);
            float loser = take ? tb1[s] : ob1;
            if (take) { tb1[s] = ob1; ti1[s] = oi1; }
            tb2[s] = fminf(fminf(tb2[s], ob2), loser);
        }
    }
    if (l15 == 0) {
        #pragma unroll
        for (int rt = 0; rt < 4; ++rt)
            #pragma unroll
            for (int r = 0; r < 4; ++r) {
                int row = rt * 16 + l4 * 4 + r;
                mb1[w][row] = tb1[rt * 4 + r];
                mb2[w][row] = tb2[rt * 4 + r];
                mi1[w][row] = ti1[rt * 4 + r];
            }
    }
    __syncthreads();

    // Merge 8 waves' top-2 per row
    if (tid < 64) {
        float B1 = 1e30f, B2 = 1e30f;
        int I1 = 0x7fffffff;
        #pragma unroll
        for (int ww = 0; ww < 8; ++ww) {
            float a1 = mb1[ww][tid], a2 = mb2[ww][tid];
            int ai = mi1[ww][tid];
            bool take = (a1 < B1) || (a1 == B1 && ai < I1);
            if (take) { B2 = fminf(B1, a2); B1 = a1; I1 = ai; }
            else      { B2 = fminf(B2, a1); }
        }
        besti[tid] = I1;
        gaps[tid] = B2 - B1;
    }
    __syncthreads();
    if (tid < 64 && gaps[tid] <= TAU) {
        int p = atomicAdd(&amb_cnt, 1);
        amb_rows[p] = tid;
    }
    __syncthreads();

    // fp64 exact refinement of ambiguous rows (block-wide, 2 codes/thread)
    for (int a = 0; a < amb_cnt; ++a) {
        int row = amb_rows[a];
        int sw = (row & 7) << 2;
        double bd = 1e300;
        int bi = 0x7fffffff;
        #pragma unroll
        for (int jj = 0; jj < 2; ++jj) {
            int k = jj * 512 + tid;
            const float* er = embed + (size_t)k * CDIM;
            double dot = 0.0;
            for (int c = 0; c < CDIM; ++c)
                dot = fma((double)er[c], (double)x_lds[row * 256 + (c ^ sw)], dot);
            double d = e2d[k] - 2.0 * dot;
            if (d < bd || (d == bd && k < bi)) { bd = d; bi = k; }
        }
        #pragma unroll
        for (int off = 1; off < 64; off <<= 1) {
            double od = __shfl_xor(bd, off);
            int oi = __shfl_xor(bi, off);
            if (od < bd || (od == bd && oi < bi)) { bd = od; bi = oi; }
        }
        if (l == 0) { red_d[w] = bd; red_i[w] = bi; }
        __syncthreads();
        if (tid == 0) {
            double fb = red_d[0];
            int fi = red_i[0];
            #pragma unroll
            for (int ww = 1; ww < 8; ++ww)
                if (red_d[ww] < fb || (red_d[ww] == fb && red_i[ww] < fi)) { fb = red_d[ww]; fi = red_i[ww]; }
            besti[row] = fi;
        }
        __syncthreads();
    }

    if (tid < 64) {
        int n = n0 + tid;
        int k = besti[tid];
        idx_out[n] = k;
        idx_f_out[n] = (float)k;
        atomicAdd(&counts[k], 1u);
    }
}

// Gather z_q, straight-through out (x + (q-x)), sum((q-x)^2) in double.
#define GBLOCKS 1024
#define GITERS 8
__global__ __launch_bounds__(256) void gather_kernel(
        const float* __restrict__ z_e, const float* __restrict__ embed,
        const int* __restrict__ idx, float* __restrict__ out,
        double* __restrict__ loss_sum) {
    double sacc = 0.0;
    #pragma unroll
    for (int it = 0; it < GITERS; ++it) {
        int f = (blockIdx.x * GITERS + it) * 256 + threadIdx.x;
        int o = f << 2;
        int hw = o & (HW - 1);
        int c = (o >> 10) & (CDIM - 1);
        int b = o >> 18;
        int n0 = (b << 10) | hw;
        int4 k4 = *(const int4*)&idx[n0];
        float4 x4 = *(const float4*)&z_e[o];
        float q0 = embed[(size_t)k4.x * CDIM + c];
        float q1 = embed[(size_t)k4.y * CDIM + c];
        float q2 = embed[(size_t)k4.z * CDIM + c];
        float q3 = embed[(size_t)k4.w * CDIM + c];
        float r0 = q0 - x4.x, r1 = q1 - x4.y, r2 = q2 - x4.z, r3 = q3 - x4.w;
        float4 o4 = make_float4(x4.x + r0, x4.y + r1, x4.z + r2, x4.w + r3);
        *(float4*)&out[o] = o4;
        sacc += (double)r0 * r0 + (double)r1 * r1 + (double)r2 * r2 + (double)r3 * r3;
    }
    __shared__ double red[4];
    #pragma unroll
    for (int off = 32; off; off >>= 1) sacc += __shfl_down(sacc, off);
    if ((threadIdx.x & 63) == 0) red[threadIdx.x >> 6] = sacc;
    __syncthreads();
    if (threadIdx.x == 0)
        atomicAdd(loss_sum, red[0] + red[1] + red[2] + red[3]);
}

__global__ __launch_bounds__(256) void finalize_kernel(
        const unsigned* __restrict__ counts, const double* __restrict__ loss_sum,
        float* __restrict__ out) {
    int tid = threadIdx.x;
    float H = 0.f;
    for (int k = tid; k < KCODES; k += 256) {
        float p = (float)counts[k] / 32768.0f;
        H += p * logf(p + 1e-10f);
    }
    __shared__ float hr[4];
    #pragma unroll
    for (int off = 32; off; off >>= 1) H += __shfl_down(H, off);
    if ((tid & 63) == 0) hr[tid >> 6] = H;
    __syncthreads();
    if (tid == 0) {
        float Hs = hr[0] + hr[1] + hr[2] + hr[3];
        out[OUT_LOSS_OFF] = (float)(0.25 * (loss_sum[0] / (double)ZELEMS));
        out[OUT_PERP_OFF] = expf(-Hs);
    }
}

extern "C" void kernel_launch(void* const* d_in, const int* in_sizes, int n_in,
                              void* d_out, int out_size, void* d_ws, size_t ws_size,
                              hipStream_t stream) {
    const float* z_e = (const float*)d_in[0];
    const float* embed = (const float*)d_in[1];
    float* out = (float*)d_out;

    char* ws = (char*)d_ws;
    int* ws_idx = (int*)(ws + WS_IDX_OFF);
    unsigned* ws_cnt = (unsigned*)(ws + WS_CNT_OFF);
    double* ws_e2d = (double*)(ws + WS_E2D_OFF);
    float* ws_e2f = (float*)(ws + WS_E2F_OFF);
    double* ws_loss = (double*)(ws + WS_LOSS_OFF);
    ushort* ws_ehi = (ushort*)(ws + WS_EHI_OFF);
    ushort* ws_elo = (ushort*)(ws + WS_ELO_OFF);

    zero_kernel<<<1, 1024, 0, stream>>>(ws_cnt, ws_loss);
    e2split_kernel<<<KCODES, 64, 0, stream>>>(embed, ws_e2d, ws_e2f, ws_ehi, ws_elo);
    argmin_kernel<<<NROWS / 64, 512, 0, stream>>>(z_e, embed, ws_ehi, ws_elo, ws_e2f,
                                                  ws_e2d, ws_idx, out + OUT_IDX_OFF, ws_cnt);
    gather_kernel<<<GBLOCKS, 256, 0, stream>>>(z_e, embed, ws_idx, out + OUT_ZQ_OFF,
                                               ws_loss);
    finalize_kernel<<<1, 256, 0, stream>>>(ws_cnt, ws_loss, out);
}

// Round 7
// 315.225 us; speedup vs baseline: 3.3663x; 1.5539x over previous
//
#include <hip/hip_runtime.h>
#include <math.h>

typedef __attribute__((ext_vector_type(8))) short short8;  // 8 bf16
typedef __attribute__((ext_vector_type(4))) float f32x4;   // MFMA C/D

#define NB 32
#define CDIM 256
#define HW 1024
#define NROWS 32768
#define KCODES 1024
#define ZELEMS 8388608

#define OUT_ZQ_OFF 0
#define OUT_IDX_OFF 8388608
#define OUT_LOSS_OFF 8421376
#define OUT_PERP_OFF 8421377

// Workspace layout (bytes)
#define WS_IDX_OFF 0            // int idx[32768]
#define WS_CNT_OFF 131072       // uint counts[1024]
#define WS_E2D_OFF 135168       // double e2d[1024]
#define WS_E2F_OFF 143360       // float e2f[1024]
#define WS_LOSS_OFF 147456      // double loss_sum
#define WS_E2MAX_OFF 147464     // float e2max (max ||e||^2)
#define WS_BHI_OFF 262144       // bf16 b_hi[1024][256] (512 KB)

#define BRN 32        // rows per argmin block
#define CAND_MAX 64

__device__ inline ushort f2bf(float f) {  // fp32 -> bf16 bits, RNE
    unsigned u = __float_as_uint(f);
    unsigned r = (u + 0x7FFFu + ((u >> 16) & 1u)) >> 16;
    return (ushort)r;
}

__global__ __launch_bounds__(1024, 1) void zero_kernel(unsigned* counts, double* loss_sum,
                                                       float* e2max) {
    int t = threadIdx.x;
    if (t < KCODES) counts[t] = 0u;
    if (t == 0) { loss_sum[0] = 0.0; e2max[0] = 0.f; }
}

// Per code k: e2 (double+float), bf16-hi row, and global max ||e||^2.
__global__ __launch_bounds__(64) void e2split_kernel(const float* __restrict__ embed,
                                                     double* __restrict__ e2d,
                                                     float* __restrict__ e2f,
                                                     ushort* __restrict__ bhi,
                                                     float* __restrict__ e2max) {
    int k = blockIdx.x, t = threadIdx.x;
    float4 v = *(const float4*)&embed[(size_t)k * CDIM + 4 * t];
    double s = (double)v.x * v.x + (double)v.y * v.y + (double)v.z * v.z + (double)v.w * v.w;
    #pragma unroll
    for (int off = 32; off; off >>= 1) s += __shfl_down(s, off);
    float xs[4] = {v.x, v.y, v.z, v.w};
    ushort h[4];
    #pragma unroll
    for (int j = 0; j < 4; ++j) h[j] = f2bf(xs[j]);
    uint2 hh;
    hh.x = (unsigned)h[0] | ((unsigned)h[1] << 16);
    hh.y = (unsigned)h[2] | ((unsigned)h[3] << 16);
    *(uint2*)&bhi[(size_t)k * CDIM + 4 * t] = hh;
    if (t == 0) {
        e2d[k] = s;
        e2f[k] = (float)s;
        atomicMax((unsigned*)e2max, __float_as_uint((float)s));  // positive floats
    }
}

// Fused distance + argmin: bf16-hi MFMA screening + exact candidate refine.
// Block: 512 thr (8 waves, wave w owns codes w*128..+127), 32 rows, all K=256 in regs.
__global__ __launch_bounds__(512, 3) void argmin_kernel(
        const float* __restrict__ z_e, const float* __restrict__ embed,
        const ushort* __restrict__ bhi, const float* __restrict__ e2f,
        const double* __restrict__ e2d, const float* __restrict__ e2max,
        int* __restrict__ idx_out, float* __restrict__ idx_f_out,
        unsigned* __restrict__ counts) {
    __shared__ float xf[BRN][CDIM + 1];          // fp32 x tile (refine + x2), padded
    __shared__ ushort ahl[BRN * CDIM];           // bf16-hi, [row][c8^(row&7) swizzle]
    __shared__ float e2s[KCODES];
    __shared__ float mb1[8][BRN], mb2[8][BRN];
    __shared__ int mi1[8][BRN];
    __shared__ int besti[BRN];
    __shared__ float b1s[BRN], taus2[BRN];
    __shared__ int amb_cnt, amb_rows[BRN];
    __shared__ int ccnt;
    __shared__ int cand_k[CAND_MAX];
    __shared__ double cand_d[CAND_MAX];
    __shared__ double red_d[8];
    __shared__ int red_i[8];

    const int tid = threadIdx.x;
    const int w = tid >> 6;
    const int l = tid & 63;
    const int l15 = l & 15, l4 = l >> 4;

    const int n0 = blockIdx.x * BRN;
    const int bB = n0 >> 10;
    const int hw0 = n0 & (HW - 1);

    // ---- Stage: z_e slice -> xf (fp32) + ahl (bf16, swizzled); e2f -> LDS ----
    #pragma unroll
    for (int i = 0; i < 2; ++i) e2s[i * 512 + tid] = e2f[i * 512 + tid];
    #pragma unroll
    for (int i = 0; i < 4; ++i) {
        int f4 = i * 512 + tid;            // 0..2047
        int c = f4 >> 3;
        int r4 = (f4 & 7) << 2;
        float4 v = *(const float4*)&z_e[(size_t)bB * (CDIM * HW) + (size_t)c * HW + hw0 + r4];
        float vv[4] = {v.x, v.y, v.z, v.w};
        #pragma unroll
        for (int j = 0; j < 4; ++j) {
            int row = r4 + j;
            xf[row][c] = vv[j];
            ahl[row * CDIM + ((((c >> 3) ^ (row & 7)) << 3) | (c & 7))] = f2bf(vv[j]);
        }
    }
    if (tid == 0) amb_cnt = 0;
    __syncthreads();

    if (tid < BRN) {  // per-row ||x||^2 -> 2*TAU (rigorous hi-only error bound)
        float s = 0.f;
        for (int c = 0; c < CDIM; ++c) s += xf[tid][c] * xf[tid][c];
        taus2[tid] = 2.f * (0.0079f * sqrtf(s * e2max[0]) + 0.02f);
    }

    // ---- MFMA screening: d_hi = e2 - 2 * (x_hi . e_hi) ----
    f32x4 acc[2][8];
    #pragma unroll
    for (int rt = 0; rt < 2; ++rt)
        #pragma unroll
        for (int ctl = 0; ctl < 8; ++ctl) acc[rt][ctl] = (f32x4){0.f, 0.f, 0.f, 0.f};

    const short8* B8 = (const short8*)bhi;
    #pragma unroll 2
    for (int ks = 0; ks < 8; ++ks) {
        int asw = ((ks * 4 + l4) ^ (l15 & 7)) << 3;
        short8 ah0 = *(const short8*)&ahl[(l15) * CDIM + asw];
        short8 ah1 = *(const short8*)&ahl[(16 + l15) * CDIM + asw];
        #pragma unroll
        for (int ctl = 0; ctl < 8; ++ctl) {
            short8 bh = B8[(w * 128 + ctl * 16 + l15) * 32 + ks * 4 + l4];
            acc[0][ctl] = __builtin_amdgcn_mfma_f32_16x16x32_bf16(ah0, bh, acc[0][ctl], 0, 0, 0);
            acc[1][ctl] = __builtin_amdgcn_mfma_f32_16x16x32_bf16(ah1, bh, acc[1][ctl], 0, 0, 0);
        }
    }

    // ---- Fold to per-row top-2 (lane holds row rt*16+l4*4+r, code w*128+ctl*16+l15) ----
    float tb1[8], tb2[8];
    int ti1[8];
    #pragma unroll
    for (int s = 0; s < 8; ++s) { tb1[s] = 1e30f; tb2[s] = 1e30f; ti1[s] = 0x7fffffff; }
    #pragma unroll
    for (int ctl = 0; ctl < 8; ++ctl) {
        int k = w * 128 + ctl * 16 + l15;
        float e2v = e2s[k];
        #pragma unroll
        for (int rt = 0; rt < 2; ++rt)
            #pragma unroll
            for (int r = 0; r < 4; ++r) {
                int s = rt * 4 + r;
                float d = fmaf(-2.f, acc[rt][ctl][r], e2v);
                bool lt = d < tb1[s];  // k ascends with ctl: strict < keeps smallest k
                tb2[s] = lt ? tb1[s] : fminf(tb2[s], d);
                if (lt) { tb1[s] = d; ti1[s] = k; }
            }
    }
    #pragma unroll
    for (int s = 0; s < 8; ++s) {
        #pragma unroll
        for (int off = 1; off < 16; off <<= 1) {
            float ob1 = __shfl_xor(tb1[s], off, 16);
            int oi1 = __shfl_xor(ti1[s], off, 16);
            float ob2 = __shfl_xor(tb2[s], off, 16);
            bool take = (ob1 < tb1[s]) || (ob1 == tb1[s] && oi1 < ti1[s]);
            float loser = take ? tb1[s] : ob1;
            if (take) { tb1[s] = ob1; ti1[s] = oi1; }
            tb2[s] = fminf(fminf(tb2[s], ob2), loser);
        }
    }
    if (l15 == 0) {
        #pragma unroll
        for (int rt = 0; rt < 2; ++rt)
            #pragma unroll
            for (int r = 0; r < 4; ++r) {
                int row = rt * 16 + l4 * 4 + r;
                mb1[w][row] = tb1[rt * 4 + r];
                mb2[w][row] = tb2[rt * 4 + r];
                mi1[w][row] = ti1[rt * 4 + r];
            }
    }
    __syncthreads();

    if (tid < BRN) {  // merge 8 waves; detect ambiguity: gap <= 2*TAU
        float B1 = 1e30f, B2 = 1e30f;
        int I1 = 0x7fffffff;
        #pragma unroll
        for (int ww = 0; ww < 8; ++ww) {
            float a1 = mb1[ww][tid], a2 = mb2[ww][tid];
            int ai = mi1[ww][tid];
            bool take = (a1 < B1) || (a1 == B1 && ai < I1);
            if (take) { B2 = fminf(B1, a2); B1 = a1; I1 = ai; }
            else      { B2 = fminf(B2, a1); }
        }
        besti[tid] = I1;
        b1s[tid] = B1;
        if (B2 - B1 <= taus2[tid]) {
            int p = atomicAdd(&amb_cnt, 1);
            amb_rows[p] = tid;
        }
    }
    __syncthreads();

    // ---- Exact refine of ambiguous rows via candidate set ----
    const int namb = amb_cnt;
    for (int a = 0; a < namb; ++a) {
        const int row = amb_rows[a];
        if (tid == 0) ccnt = 0;
        __syncthreads();
        {   // scan this lane's d_hi values for codes within best + 2*TAU
            const int lq = (row >> 2) & 3, rtw = row >> 4, rw = row & 3;
            const float lim = b1s[row] + taus2[row];
            if (l4 == lq) {
                #pragma unroll
                for (int rt = 0; rt < 2; ++rt)
                    #pragma unroll
                    for (int r = 0; r < 4; ++r)
                        if (rt == rtw && r == rw) {
                            #pragma unroll
                            for (int ctl = 0; ctl < 8; ++ctl) {
                                int k = w * 128 + ctl * 16 + l15;
                                float d = fmaf(-2.f, acc[rt][ctl][r], e2s[k]);
                                if (d <= lim) {
                                    int p = atomicAdd(&ccnt, 1);
                                    if (p < CAND_MAX) cand_k[p] = k;
                                }
                            }
                        }
            }
        }
        __syncthreads();
        const int nc = ccnt;
        if (nc > CAND_MAX) {
            // overflow fallback: full exact fp64 row (ultra-rare)
            double bd = 1e300;
            int bi = 0x7fffffff;
            #pragma unroll
            for (int jj = 0; jj < 2; ++jj) {
                int k = jj * 512 + tid;
                const float* er = embed + (size_t)k * CDIM;
                double dot = 0.0;
                for (int c = 0; c < CDIM; ++c)
                    dot = fma((double)er[c], (double)xf[row][c], dot);
                double d = e2d[k] - 2.0 * dot;
                if (d < bd || (d == bd && k < bi)) { bd = d; bi = k; }
            }
            #pragma unroll
            for (int off = 1; off < 64; off <<= 1) {
                double od = __shfl_xor(bd, off);
                int oi = __shfl_xor(bi, off);
                if (od < bd || (od == bd && oi < bi)) { bd = od; bi = oi; }
            }
            if (l == 0) { red_d[w] = bd; red_i[w] = bi; }
            __syncthreads();
            if (tid == 0) {
                double fb = red_d[0];
                int fi = red_i[0];
                #pragma unroll
                for (int ww = 1; ww < 8; ++ww)
                    if (red_d[ww] < fb || (red_d[ww] == fb && red_i[ww] < fi)) { fb = red_d[ww]; fi = red_i[ww]; }
                besti[row] = fi;
            }
        } else {
            // exact fp64 for nc candidates: wave per candidate (round-robin)
            for (int ci = w; ci < nc; ci += 8) {
                int k = cand_k[ci];
                float4 e4 = *(const float4*)&embed[(size_t)k * CDIM + 4 * l];
                double dot = (double)e4.x * xf[row][4 * l + 0] + (double)e4.y * xf[row][4 * l + 1] +
                             (double)e4.z * xf[row][4 * l + 2] + (double)e4.w * xf[row][4 * l + 3];
                #pragma unroll
                for (int off = 1; off < 64; off <<= 1) dot += __shfl_xor(dot, off);
                if (l == 0) cand_d[ci] = e2d[k] - 2.0 * dot;
            }
            __syncthreads();
            if (tid == 0) {
                double fb = 1e300;
                int fi = 0x7fffffff;
                for (int ci = 0; ci < nc; ++ci) {
                    double d = cand_d[ci];
                    int k = cand_k[ci];
                    if (d < fb || (d == fb && k < fi)) { fb = d; fi = k; }
                }
                besti[row] = fi;
            }
        }
        __syncthreads();
    }

    if (tid < BRN) {
        int n = n0 + tid;
        int k = besti[tid];
        idx_out[n] = k;
        idx_f_out[n] = (float)k;
        atomicAdd(&counts[k], 1u);
    }
}

// Gather z_q, straight-through out (x + (q-x)), sum((q-x)^2) in double.
#define GBLOCKS 1024
#define GITERS 8
__global__ __launch_bounds__(256) void gather_kernel(
        const float* __restrict__ z_e, const float* __restrict__ embed,
        const int* __restrict__ idx, float* __restrict__ out,
        double* __restrict__ loss_sum) {
    double sacc = 0.0;
    #pragma unroll
    for (int it = 0; it < GITERS; ++it) {
        int f = (blockIdx.x * GITERS + it) * 256 + threadIdx.x;
        int o = f << 2;
        int hw = o & (HW - 1);
        int c = (o >> 10) & (CDIM - 1);
        int b = o >> 18;
        int n0 = (b << 10) | hw;
        int4 k4 = *(const int4*)&idx[n0];
        float4 x4 = *(const float4*)&z_e[o];
        float q0 = embed[(size_t)k4.x * CDIM + c];
        float q1 = embed[(size_t)k4.y * CDIM + c];
        float q2 = embed[(size_t)k4.z * CDIM + c];
        float q3 = embed[(size_t)k4.w * CDIM + c];
        float r0 = q0 - x4.x, r1 = q1 - x4.y, r2 = q2 - x4.z, r3 = q3 - x4.w;
        float4 o4 = make_float4(x4.x + r0, x4.y + r1, x4.z + r2, x4.w + r3);
        *(float4*)&out[o] = o4;
        sacc += (double)r0 * r0 + (double)r1 * r1 + (double)r2 * r2 + (double)r3 * r3;
    }
    __shared__ double red[4];
    #pragma unroll
    for (int off = 32; off; off >>= 1) sacc += __shfl_down(sacc, off);
    if ((threadIdx.x & 63) == 0) red[threadIdx.x >> 6] = sacc;
    __syncthreads();
    if (threadIdx.x == 0)
        atomicAdd(loss_sum, red[0] + red[1] + red[2] + red[3]);
}

__global__ __launch_bounds__(256) void finalize_kernel(
        const unsigned* __restrict__ counts, const double* __restrict__ loss_sum,
        float* __restrict__ out) {
    int tid = threadIdx.x;
    float H = 0.f;
    for (int k = tid; k < KCODES; k += 256) {
        float p = (float)counts[k] / 32768.0f;
        H += p * logf(p + 1e-10f);
    }
    __shared__ float hr[4];
    #pragma unroll
    for (int off = 32; off; off >>= 1) H += __shfl_down(H, off);
    if ((tid & 63) == 0) hr[tid >> 6] = H;
    __syncthreads();
    if (tid == 0) {
        float Hs = hr[0] + hr[1] + hr[2] + hr[3];
        out[OUT_LOSS_OFF] = (float)(0.25 * (loss_sum[0] / (double)ZELEMS));
        out[OUT_PERP_OFF] = expf(-Hs);
    }
}

extern "C" void kernel_launch(void* const* d_in, const int* in_sizes, int n_in,
                              void* d_out, int out_size, void* d_ws, size_t ws_size,
                              hipStream_t stream) {
    const float* z_e = (const float*)d_in[0];
    const float* embed = (const float*)d_in[1];
    float* out = (float*)d_out;

    char* ws = (char*)d_ws;
    int* ws_idx = (int*)(ws + WS_IDX_OFF);
    unsigned* ws_cnt = (unsigned*)(ws + WS_CNT_OFF);
    double* ws_e2d = (double*)(ws + WS_E2D_OFF);
    float* ws_e2f = (float*)(ws + WS_E2F_OFF);
    double* ws_loss = (double*)(ws + WS_LOSS_OFF);
    float* ws_e2max = (float*)(ws + WS_E2MAX_OFF);
    ushort* ws_bhi = (ushort*)(ws + WS_BHI_OFF);

    zero_kernel<<<1, 1024, 0, stream>>>(ws_cnt, ws_loss, ws_e2max);
    e2split_kernel<<<KCODES, 64, 0, stream>>>(embed, ws_e2d, ws_e2f, ws_bhi, ws_e2max);
    argmin_kernel<<<NROWS / BRN, 512, 0, stream>>>(z_e, embed, ws_bhi, ws_e2f, ws_e2d,
                                                   ws_e2max, ws_idx, out + OUT_IDX_OFF, ws_cnt);
    gather_kernel<<<GBLOCKS, 256, 0, stream>>>(z_e, embed, ws_idx, out + OUT_ZQ_OFF,
                                               ws_loss);
    finalize_kernel<<<1, 256, 0, stream>>>(ws_cnt, ws_loss, out);
}